// Round 12
// baseline (321.765 us; speedup 1.0000x reference)
//
#include <hip/hip_runtime.h>
#include <hip/hip_bf16.h>
#include <cstdint>

#define B_ 16
#define N_ 1024
#define D_ 256
#define H_ 128

typedef unsigned short u16;
typedef __attribute__((ext_vector_type(8))) short bf16x8;
typedef __attribute__((ext_vector_type(4))) float f32x4;

__device__ __forceinline__ u16 f2bf(float f) {
    union { float f; uint32_t u; } v; v.f = f;
    return (u16)((v.u + 0x7FFFu + ((v.u >> 16) & 1u)) >> 16);  // RNE
}
__device__ __forceinline__ float bf2f(u16 h) {
    union { uint32_t u; float f; } v; v.u = ((uint32_t)h) << 16;
    return v.f;
}

typedef __attribute__((address_space(3))) void lds_void;
typedef const __attribute__((address_space(1))) void g_void;

__device__ __forceinline__ void gl_lds16(const void* g, void* l) {
    __builtin_amdgcn_global_load_lds((g_void*)g, (lds_void*)l, 16, 0, 0);
}

__device__ __forceinline__ void vm_wait8() { asm volatile("s_waitcnt vmcnt(8)" ::: "memory"); }
__device__ __forceinline__ void vm_wait4() { asm volatile("s_waitcnt vmcnt(4)" ::: "memory"); }
__device__ __forceinline__ void vm_wait3() { asm volatile("s_waitcnt vmcnt(3)" ::: "memory"); }
__device__ __forceinline__ void vm_wait0() { asm volatile("s_waitcnt vmcnt(0)" ::: "memory"); }
__device__ __forceinline__ void lgkm0()   { asm volatile("s_waitcnt lgkmcnt(0)" ::: "memory"); }
__device__ __forceinline__ void schedb()  { __builtin_amdgcn_sched_barrier(0); }

// ---------------------------------------------------------------------------
// K1: fp32 adjacencies -> bf16 (normal + transposed). 64x64 tiles, conflict-
// free swizzle (slot = g ^ ((r&7)^((r>>3)&7)); measured 0 conflicts r8).
// grid (16, 16, B*2), block 256. Accepted at its mixed R/W BW floor (~2.9TB/s).
__global__ __launch_bounds__(256) void k_conv_adj(
    const float* __restrict__ dep, const float* __restrict__ lat,
    u16* __restrict__ depb, u16* __restrict__ latb,
    u16* __restrict__ depTb, u16* __restrict__ latTb)
{
    __shared__ u16 tile[64][64];
    const int bz = blockIdx.z;
    const int b = bz >> 1;
    const float* src = (bz & 1) ? lat : dep;
    u16* dstN = (bz & 1) ? latb : depb;
    u16* dstT = (bz & 1) ? latTb : depTb;
    const int r0 = blockIdx.y * 64, c0 = blockIdx.x * 64;
    const int t = threadIdx.x;
    const int r = t >> 2, cg = (t & 3) * 16;

    const float* srow = src + ((size_t)b * N_ + r0 + r) * N_ + c0 + cg;
    bf16x8 lo, hi;
    {
        const float4 v0 = *(const float4*)(srow);
        const float4 v1 = *(const float4*)(srow + 4);
        const float4 v2 = *(const float4*)(srow + 8);
        const float4 v3 = *(const float4*)(srow + 12);
        lo[0] = (short)f2bf(v0.x); lo[1] = (short)f2bf(v0.y); lo[2] = (short)f2bf(v0.z); lo[3] = (short)f2bf(v0.w);
        lo[4] = (short)f2bf(v1.x); lo[5] = (short)f2bf(v1.y); lo[6] = (short)f2bf(v1.z); lo[7] = (short)f2bf(v1.w);
        hi[0] = (short)f2bf(v2.x); hi[1] = (short)f2bf(v2.y); hi[2] = (short)f2bf(v2.z); hi[3] = (short)f2bf(v2.w);
        hi[4] = (short)f2bf(v3.x); hi[5] = (short)f2bf(v3.y); hi[6] = (short)f2bf(v3.z); hi[7] = (short)f2bf(v3.w);
    }
    u16* nrow = dstN + ((size_t)b * N_ + r0 + r) * N_ + c0 + cg;
    *(bf16x8*)nrow = lo;
    *(bf16x8*)(nrow + 8) = hi;

    const int g0 = (t & 3) * 2;
    const int s = (r & 7) ^ ((r >> 3) & 7);
    *(bf16x8*)(&tile[r][((g0    ) ^ s) * 8]) = lo;
    *(bf16x8*)(&tile[r][((g0 + 1) ^ s) * 8]) = hi;
    __syncthreads();

    const int sc = t >> 2, rg2 = (t & 3) * 16;
    bf16x8 o0, o1;
    #pragma unroll
    for (int i = 0; i < 8; ++i) {
        const int R = rg2 + i;
        const int sR = (R & 7) ^ ((R >> 3) & 7);
        o0[i] = (short)tile[R][(((sc >> 3) ^ sR) * 8) + (sc & 7)];
    }
    #pragma unroll
    for (int i = 0; i < 8; ++i) {
        const int R = rg2 + 8 + i;
        const int sR = (R & 7) ^ ((R >> 3) & 7);
        o1[i] = (short)tile[R][(((sc >> 3) ^ sR) * 8) + (sc & 7)];
    }
    u16* dT = dstT + ((size_t)b * N_ + c0 + sc) * N_ + r0 + rg2;
    *(bf16x8*)dT = o0;
    *(bf16x8*)(dT + 8) = o1;
}

// ---------------------------------------------------------------------------
// K2: layer-0 refine gate + x0 transposed to bf16 [B, D, N]. Extra y-slices
// (y >= B, 8 of them) convert BOTH layers' FC weights (2 x H x D each).
__global__ __launch_bounds__(256) void k_gate_xt(
    const float* __restrict__ x, const float* __restrict__ rg,
    float* __restrict__ gate, u16* __restrict__ xT,
    const float* __restrict__ wi, const float* __restrict__ wo,
    u16* __restrict__ wib, u16* __restrict__ wob)
{
    if (blockIdx.y >= B_) {
        const int i = ((blockIdx.y - B_) * 32 + blockIdx.x) * 256 + threadIdx.x;  // [0, 65536)
        wib[i] = f2bf(wi[i]);
        wob[i] = f2bf(wo[i]);
        return;
    }

    __shared__ u16 lx[D_][36];
    __shared__ float srg[D_];
    const int b = blockIdx.y, n0 = blockIdx.x * 32;
    const int t = threadIdx.x;
    srg[t] = rg[t];
    __syncthreads();

    const int r = t >> 3, cg = t & 7;
    const float* xrow = x + ((size_t)b * N_ + n0 + r) * D_;
    float dot = 0.f;
    #pragma unroll
    for (int u = 0; u < 8; ++u) {
        const int c = cg * 32 + u * 4;
        const float4 v = *(const float4*)(xrow + c);
        lx[c][r] = f2bf(v.x); lx[c + 1][r] = f2bf(v.y);
        lx[c + 2][r] = f2bf(v.z); lx[c + 3][r] = f2bf(v.w);
        dot += v.x * srg[c] + v.y * srg[c + 1] + v.z * srg[c + 2] + v.w * srg[c + 3];
    }
    dot += __shfl_down(dot, 4, 8);
    dot += __shfl_down(dot, 2, 8);
    dot += __shfl_down(dot, 1, 8);
    if (cg == 0) gate[(size_t)b * N_ + n0 + r] = 1.f / (1.f + expf(-dot));
    __syncthreads();

    #pragma unroll
    for (int i = 0; i < 8; ++i) {
        const int unit = i * 256 + t;
        const int d = unit >> 3, nch = (unit & 7) * 4;
        ushort4 wv;
        wv.x = lx[d][nch];     wv.y = lx[d][nch + 1];
        wv.z = lx[d][nch + 2]; wv.w = lx[d][nch + 3];
        *(ushort4*)(xT + ((size_t)b * D_ + d) * N_ + n0 + nch) = wv;
    }
}

// ---------------------------------------------------------------------------
// K3 v7: single blended GEMM, BK=64 (halves barrier events vs r8's BK=32:
// 16 bodies x 32 MFMA/wave instead of 32 x 16; same bytes, same FIFO
// discipline). Tile 128m x 256n, 8 waves, grid 256 = 1 block/CU.
// LDS 2 x 48KB (A[128][64] 16KB + B[256][64] 32KB) + tails = 100.9KB.
// Swizzle: 8 granules/row, slot = g ^ (row&7), both sides (write spread
// verified 2-way free; fragment reads 2-way free).
// FIFO: entering body(ks) = [A(ks+2)x4, B(ks+1)x4]; +A(ks+3)x4; blend's
// implicit wait retires A(ks+2); +B(ks+2)x4; explicit vmcnt(8) retires
// B(ks+1). Tail ks=13: vmcnt(4); ks=14: vmcnt(0); ks=15: none.
__global__ __launch_bounds__(512, 2) void k_gemm_ax(
    const u16* __restrict__ depb, const u16* __restrict__ latb,
    const u16* __restrict__ depTb, const u16* __restrict__ latTb,
    const u16* __restrict__ xT,
    const float* __restrict__ gate,
    const float* __restrict__ Wgi, const float* __restrict__ Wgo,
    const float* __restrict__ bgi, const float* __restrict__ bgo,
    const float* __restrict__ xcur,
    u16* __restrict__ axin, u16* __restrict__ axout)
{
    __shared__ __align__(16) char smem[100864];
    u16* const sb = (u16*)smem;                 // 2 bufs x 24576 u16 [A 8192|B 16384]
    float* hbuf = (float*)smem;                 // epilogue alias [32][260]
    float* psum = (float*)(smem + 98304);       // [128][4]
    float* sh_s = (float*)(smem + 100352);      // [128]

    const int bid = blockIdx.x;
    const int logical = (bid & 7) * 32 + (bid >> 3);
    const int b = logical >> 4;
    const int rem = logical & 15;
    const int z = rem >> 3;
    const int m0 = (rem & 7) * 128;

    const u16* A1 = z ? depTb : depb;
    const u16* A2 = z ? latTb : latb;
    const float* Wg = z ? Wgo : Wgi;
    const float bg0 = z ? bgo[0] : bgi[0];
    u16* outp = z ? axout : axin;

    const int t = threadIdx.x;
    const int lane = t & 63;
    const int w = t >> 6;
    const int wr = w >> 2, wc = w & 3;

    // A staging: thread t -> row t>>2 (0..127), granule pair (t&3, t&3+4).
    // Dest slots = src_granule ^ (row&7) -> write banks spread (2/bank, free).
    const int arow = t >> 2;
    const int aq = t & 3;
    const float gv = gate[(size_t)b * N_ + m0 + arow];
    const u16* gA1 = A1 + ((size_t)b * N_ + m0 + arow) * N_ + aq * 8;
    const u16* gA2 = A2 + ((size_t)b * N_ + m0 + arow) * N_ + aq * 8;
    const int awoff = arow * 64 + ((aq ^ (arow & 7)) << 3);   // slot for granule aq

    // B dma: 32 chunks of 8 rows; wave w stages chunks 4w..4w+3.
    // lane l -> row chunk*8 + (l>>3), slot granule l&7, src granule XORed.
    const int kksrc = (((lane & 7) ^ ((lane >> 3) & 7)) << 3);
    const u16* gB[4];
    int boff[4];
    #pragma unroll
    for (int j = 0; j < 4; ++j) {
        const int ch = w * 4 + j;
        gB[j] = xT + ((size_t)b * D_ + ch * 8 + (lane >> 3)) * N_ + kksrc;
        boff[j] = 8192 + ch * 512;
    }

    const int mrow = lane & 15;
    const int hi = lane >> 4;

    f32x4 acc[4][4];
    const f32x4 fz = {0.f, 0.f, 0.f, 0.f};
    #pragma unroll
    for (int i = 0; i < 4; ++i)
        #pragma unroll
        for (int j = 0; j < 4; ++j) acc[i][j] = fz;

    struct S { bf16x8 a1l, a1h, a2l, a2h; };
    S sx, sy;

    auto loadA = [&](S& s, int ks) {
        s.a1l = *(const bf16x8*)(gA1 + ks * 64);
        s.a1h = *(const bf16x8*)(gA1 + ks * 64 + 32);
        s.a2l = *(const bf16x8*)(gA2 + ks * 64);
        s.a2h = *(const bf16x8*)(gA2 + ks * 64 + 32);
    };
    auto blend8 = [&](const bf16x8& a1v, const bf16x8& a2v) {
        bf16x8 bl;
        #pragma unroll
        for (int u = 0; u < 8; ++u) {
            const float f1 = bf2f((u16)a1v[u]);
            const float f2 = bf2f((u16)a2v[u]);
            bl[u] = (short)f2bf(f2 + gv * (f1 - f2));
        }
        return bl;
    };
    auto blend_store = [&](const S& s, u16* cb) {
        *(bf16x8*)(cb + awoff) = blend8(s.a1l, s.a2l);          // granule aq
        *(bf16x8*)(cb + (awoff ^ 32)) = blend8(s.a1h, s.a2h);   // granule aq+4
    };

    // prologue: tiles 0,1 staged; A(2) regs + B(0),B(1) dmas in flight
    loadA(sx, 0); blend_store(sx, sb);                    // A(0) -> buf0
    loadA(sx, 1); blend_store(sx, sb + 24576);            // A(1) -> buf1
    #pragma unroll
    for (int j = 0; j < 4; ++j) gl_lds16(gB[j], sb + boff[j]);             // B(0)
    loadA(sx, 2);                                         // A(2) regs
    #pragma unroll
    for (int j = 0; j < 4; ++j) gl_lds16(gB[j] + 64, sb + 24576 + boff[j]); // B(1)
    vm_wait8();   // FIFO [B0x4, A2x4, B1x4] -> retire B(0)
    lgkm0();
    schedb(); __builtin_amdgcn_s_barrier(); schedb();

    auto body = [&](int ks, S& cS, S& nS) {
        if (ks <= 12) loadA(nS, ks + 3);                  // issue A(ks+3)
        const u16* sA = sb + (ks & 1) * 24576;
        const u16* sBc = sA + 8192;
        #pragma unroll
        for (int kh = 0; kh < 2; ++kh) {
            bf16x8 a[4], fbv[4];
            #pragma unroll
            for (int mt = 0; mt < 4; ++mt) {
                const int row = wr * 64 + mt * 16 + mrow;
                const int slot = (kh * 4 + hi) ^ (mrow & 7);
                a[mt] = *(const bf16x8*)(sA + row * 64 + slot * 8);
            }
            #pragma unroll
            for (int nt = 0; nt < 4; ++nt) {
                const int row = wc * 64 + nt * 16 + mrow;
                const int slot = (kh * 4 + hi) ^ (mrow & 7);
                fbv[nt] = *(const bf16x8*)(sBc + row * 64 + slot * 8);
            }
            #pragma unroll
            for (int mt = 0; mt < 4; ++mt)
                #pragma unroll
                for (int nt = 0; nt < 4; ++nt)
                    acc[mt][nt] = __builtin_amdgcn_mfma_f32_16x16x32_bf16(a[mt], fbv[nt], acc[mt][nt], 0, 0, 0);
        }
        schedb();
        __builtin_amdgcn_s_barrier();       // all waves done reading cur
        schedb();
        if (ks <= 13) {                      // tile ks+2 -> cur buffer
            u16* cb = sb + (ks & 1) * 24576;
            blend_store(cS, cb);             // implicit wait retires A(ks+2)x4
            #pragma unroll
            for (int j = 0; j < 4; ++j) gl_lds16(gB[j] + (ks + 2) * 64, cb + boff[j]);
        }
        if (ks <= 12) vm_wait8();            // retire B(ks+1); keep A(ks+3)+B(ks+2)
        else if (ks == 13) vm_wait4();       // retire B(14); keep B(15)
        else if (ks == 14) vm_wait0();       // retire B(15)
        lgkm0();
        schedb();
        __builtin_amdgcn_s_barrier();
        schedb();
    };

    for (int kp = 0; kp < 8; ++kp) {
        body(2 * kp,     sx, sy);
        body(2 * kp + 1, sy, sx);
    }
    __syncthreads();

    // gcn-gate: full-row dot from acc regs
    float wgv[4];
    #pragma unroll
    for (int nt = 0; nt < 4; ++nt) wgv[nt] = Wg[wc * 64 + nt * 16 + mrow];
    #pragma unroll
    for (int mt = 0; mt < 4; ++mt) {
        #pragma unroll
        for (int rr = 0; rr < 4; ++rr) {
            float p = acc[mt][0][rr] * wgv[0] + acc[mt][1][rr] * wgv[1]
                    + acc[mt][2][rr] * wgv[2] + acc[mt][3][rr] * wgv[3];
            p += __shfl_xor(p, 1, 16);
            p += __shfl_xor(p, 2, 16);
            p += __shfl_xor(p, 4, 16);
            p += __shfl_xor(p, 8, 16);
            if (mrow == 0) psum[(wr * 64 + mt * 16 + hi * 4 + rr) * 4 + wc] = p;
        }
    }
    __syncthreads();
    if (t < 128) {
        const float d = psum[t * 4] + psum[t * 4 + 1] + psum[t * 4 + 2] + psum[t * 4 + 3];
        sh_s[t] = 1.f / (1.f + expf(-d));
    }
    __syncthreads();

    // 4 store passes of 32 rows each
    #pragma unroll
    for (int p = 0; p < 4; ++p) {
        if (wr == (p >> 1)) {
            #pragma unroll
            for (int mtl = 0; mtl < 2; ++mtl) {
                const int mt = (p & 1) * 2 + mtl;
                #pragma unroll
                for (int nt = 0; nt < 4; ++nt) {
                    const int col = wc * 64 + nt * 16 + mrow;
                    #pragma unroll
                    for (int rr = 0; rr < 4; ++rr) {
                        const int hrow = mtl * 16 + hi * 4 + rr;
                        hbuf[hrow * 260 + col] = acc[mt][nt][rr];
                    }
                }
            }
        }
        __syncthreads();
        {
            const int sr = t >> 4;
            const int sc0 = (t & 15) * 16;
            const int grow = p * 32 + sr;
            const float s = sh_s[grow];
            const size_t gb = ((size_t)b * N_ + m0 + grow) * D_ + sc0;
            const float* xr = xcur + gb;
            u16* orow = outp + gb;
            bf16x8 o0, o1;
            #pragma unroll
            for (int u = 0; u < 8; ++u)
                o0[u] = (short)f2bf(hbuf[sr * 260 + sc0 + u] * s + bg0 + xr[u]);
            #pragma unroll
            for (int u = 0; u < 8; ++u)
                o1[u] = (short)f2bf(hbuf[sr * 260 + sc0 + 8 + u] * s + bg0 + xr[8 + u]);
            *(bf16x8*)orow = o0;
            *(bf16x8*)(orow + 8) = o1;
        }
        __syncthreads();
    }
}

// ---------------------------------------------------------------------------
// K4: gemm-skeleton fc_ln (round-8 core). Tile 64m x 256n, 8 waves, grid 256.
// FUSE=1 (layer 0): also computes next layer's refine gate and emits bf16
// transposed xT — eliminating the layer-1 k_gate_xt launch + 64MB re-read.
template<int FUSE>
__global__ __launch_bounds__(512, 2) void k_fc_ln(
    const u16* __restrict__ axin, const u16* __restrict__ axout,
    const u16* __restrict__ Wib, const u16* __restrict__ Wob,
    const float* __restrict__ bi, const float* __restrict__ bo,
    const float* __restrict__ lg, const float* __restrict__ lb,
    float* __restrict__ outp,
    const float* __restrict__ rgN, float* __restrict__ gateN,
    u16* __restrict__ xTN)
{
    __shared__ __align__(16) char smem[51712];
    u16* const sb = (u16*)smem;
    float* hbuf = (float*)smem;
    float* psum = (float*)(smem + 49152);
    float* sh_mu = (float*)(smem + 51200);
    float* sh_rs = (float*)(smem + 51456);

    const int bid = blockIdx.x;
    const int logical = (bid & 7) * 32 + (bid >> 3);
    const int b = logical >> 4;
    const int m0 = (logical & 15) * 64;

    const int t = threadIdx.x, lane = t & 63, w = t >> 6;
    const int wr = w >> 2, wc = w & 3;
    const int half = wc >> 1;

    const int rl = lane >> 2;
    const int kk = (((lane & 3) ^ ((lane >> 3) & 3)) << 3);

    const u16* gsrc[3];
    int loff[3];
    #pragma unroll
    for (int ci = 0; ci < 3; ++ci) {
        const int c = w * 3 + ci;
        if (c < 4) {
            gsrc[ci] = axin + ((size_t)b * N_ + m0 + c * 16 + rl) * D_ + kk;
            loff[ci] = c * 512;
        } else if (c < 8) {
            gsrc[ci] = axout + ((size_t)b * N_ + m0 + (c - 4) * 16 + rl) * D_ + kk;
            loff[ci] = 2048 + (c - 4) * 512;
        } else {
            const int cw = c - 8;
            const u16* base = (cw < 8) ? (Wib + (size_t)(cw * 16 + rl) * D_)
                                       : (Wob + (size_t)((cw - 8) * 16 + rl) * D_);
            gsrc[ci] = base + kk;
            loff[ci] = 4096 + cw * 512;
        }
    }

    f32x4 acc[2][4];
    const f32x4 fz = {0.f, 0.f, 0.f, 0.f};
    #pragma unroll
    for (int i = 0; i < 2; ++i)
        #pragma unroll
        for (int j = 0; j < 4; ++j) acc[i][j] = fz;

    #pragma unroll
    for (int ci = 0; ci < 3; ++ci) gl_lds16(gsrc[ci], sb + loff[ci]);
    #pragma unroll
    for (int ci = 0; ci < 3; ++ci) gl_lds16(gsrc[ci] + 32, sb + 12288 + loff[ci]);
    vm_wait3();
    lgkm0();
    schedb(); __builtin_amdgcn_s_barrier(); schedb();

    const int mrow = lane & 15;
    const int hi = lane >> 4;
    const int kg = (((lane >> 4) ^ ((mrow >> 1) & 3)) << 3);

    for (int ks = 0; ks < 8; ++ks) {
        const u16* cur = sb + (ks & 1) * 12288;
        const u16* sA = cur + (half ? 2048 : 0);
        const u16* sW = cur + 4096;
        bf16x8 a[2], fbv[4];
        #pragma unroll
        for (int mt = 0; mt < 2; ++mt)
            a[mt] = *(const bf16x8*)(sA + (wr * 32 + mt * 16 + mrow) * 32 + kg);
        #pragma unroll
        for (int nt = 0; nt < 4; ++nt)
            fbv[nt] = *(const bf16x8*)(sW + (wc * 64 + nt * 16 + mrow) * 32 + kg);
        #pragma unroll
        for (int mt = 0; mt < 2; ++mt)
            #pragma unroll
            for (int nt = 0; nt < 4; ++nt)
                acc[mt][nt] = __builtin_amdgcn_mfma_f32_16x16x32_bf16(a[mt], fbv[nt], acc[mt][nt], 0, 0, 0);
        schedb();
        __builtin_amdgcn_s_barrier();
        schedb();
        if (ks <= 5) {
            u16* nb = sb + (ks & 1) * 12288;
            #pragma unroll
            for (int ci = 0; ci < 3; ++ci) gl_lds16(gsrc[ci] + (ks + 2) * 32, nb + loff[ci]);
        }
        if (ks <= 5) vm_wait3();
        else if (ks == 6) vm_wait0();
        lgkm0();
        schedb();
        __builtin_amdgcn_s_barrier();
        schedb();
    }
    __syncthreads();

    float bc[4];
    #pragma unroll
    for (int nt = 0; nt < 4; ++nt) {
        const int colh = wc * 64 + nt * 16 + mrow;
        bc[nt] = 2.f * (colh < 128 ? bi[colh] : bo[colh - 128]);
    }
    #pragma unroll
    for (int mt = 0; mt < 2; ++mt)
        #pragma unroll
        for (int rr = 0; rr < 4; ++rr) {
            const int lrow = wr * 32 + mt * 16 + hi * 4 + rr;
            float s = 0.f, ss = 0.f;
            #pragma unroll
            for (int nt = 0; nt < 4; ++nt) {
                const float v = acc[mt][nt][rr] + bc[nt];
                s += v; ss += v * v;
            }
            s += __shfl_xor(s, 1, 16);  ss += __shfl_xor(ss, 1, 16);
            s += __shfl_xor(s, 2, 16);  ss += __shfl_xor(ss, 2, 16);
            s += __shfl_xor(s, 4, 16);  ss += __shfl_xor(ss, 4, 16);
            s += __shfl_xor(s, 8, 16);  ss += __shfl_xor(ss, 8, 16);
            if (mrow == 0) {
                psum[lrow * 8 + wc * 2] = s;
                psum[lrow * 8 + wc * 2 + 1] = ss;
            }
        }
    __syncthreads();
    if (t < 64) {
        const float s = psum[t * 8] + psum[t * 8 + 2] + psum[t * 8 + 4] + psum[t * 8 + 6];
        const float ss = psum[t * 8 + 1] + psum[t * 8 + 3] + psum[t * 8 + 5] + psum[t * 8 + 7];
        const float mu = s * (1.f / 256.f);
        const float var = ss * (1.f / 256.f) - mu * mu;
        sh_mu[t] = mu;
        sh_rs[t] = rsqrtf(var + 1e-5f);
    }
    __syncthreads();

    #pragma unroll
    for (int p = 0; p < 2; ++p) {
        if (wr == p) {
            #pragma unroll
            for (int mt = 0; mt < 2; ++mt)
                #pragma unroll
                for (int nt = 0; nt < 4; ++nt) {
                    const int col = wc * 64 + nt * 16 + mrow;
                    #pragma unroll
                    for (int rr = 0; rr < 4; ++rr) {
                        const int hrow = mt * 16 + hi * 4 + rr;
                        hbuf[hrow * 260 + col] = acc[mt][nt][rr] + bc[nt];
                    }
                }
        }
        __syncthreads();
        {
            const int sr = t >> 4;
            const int sc0 = (t & 15) * 16;
            const int grow = p * 32 + sr;
            const float mu = sh_mu[grow], rs = sh_rs[grow];
            float* orow = outp + ((size_t)b * N_ + m0 + grow) * D_ + sc0;
            float gdot = 0.f;
            #pragma unroll
            for (int q = 0; q < 4; ++q) {
                const float4 gg = *(const float4*)(lg + sc0 + q * 4);
                const float4 bb = *(const float4*)(lb + sc0 + q * 4);
                float4 o;
                const float v0 = (hbuf[sr * 260 + sc0 + q * 4    ] - mu) * rs * gg.x + bb.x;
                const float v1 = (hbuf[sr * 260 + sc0 + q * 4 + 1] - mu) * rs * gg.y + bb.y;
                const float v2 = (hbuf[sr * 260 + sc0 + q * 4 + 2] - mu) * rs * gg.z + bb.z;
                const float v3 = (hbuf[sr * 260 + sc0 + q * 4 + 3] - mu) * rs * gg.w + bb.w;
                o.x = 0.5f * v0 * (1.f + erff(v0 * 0.70710678118654752f));
                o.y = 0.5f * v1 * (1.f + erff(v1 * 0.70710678118654752f));
                o.z = 0.5f * v2 * (1.f + erff(v2 * 0.70710678118654752f));
                o.w = 0.5f * v3 * (1.f + erff(v3 * 0.70710678118654752f));
                *(float4*)(orow + q * 4) = o;
                if (FUSE) {
                    hbuf[sr * 260 + sc0 + q * 4    ] = o.x;
                    hbuf[sr * 260 + sc0 + q * 4 + 1] = o.y;
                    hbuf[sr * 260 + sc0 + q * 4 + 2] = o.z;
                    hbuf[sr * 260 + sc0 + q * 4 + 3] = o.w;
                    const float4 rv = *(const float4*)(rgN + sc0 + q * 4);
                    gdot += o.x * rv.x + o.y * rv.y + o.z * rv.z + o.w * rv.w;
                }
            }
            if (FUSE) {
                gdot += __shfl_xor(gdot, 1, 16);
                gdot += __shfl_xor(gdot, 2, 16);
                gdot += __shfl_xor(gdot, 4, 16);
                gdot += __shfl_xor(gdot, 8, 16);
                if ((t & 15) == 0)
                    gateN[(size_t)b * N_ + m0 + grow] = 1.f / (1.f + expf(-gdot));
            }
        }
        __syncthreads();
        if (FUSE) {
            const int d = t >> 1;
            const int nh = (t & 1) * 16;
            bf16x8 y0, y1;
            #pragma unroll
            for (int i = 0; i < 8; ++i)
                y0[i] = (short)f2bf(hbuf[(nh + i) * 260 + d]);
            #pragma unroll
            for (int i = 0; i < 8; ++i)
                y1[i] = (short)f2bf(hbuf[(nh + 8 + i) * 260 + d]);
            u16* xrow = xTN + ((size_t)b * D_ + d) * N_ + m0 + p * 32 + nh;
            *(bf16x8*)xrow = y0;
            *(bf16x8*)(xrow + 8) = y1;
            __syncthreads();
        }
    }
}

// ---------------------------------------------------------------------------
extern "C" void kernel_launch(void* const* d_in, const int* in_sizes, int n_in,
                              void* d_out, int out_size, void* d_ws, size_t ws_size,
                              hipStream_t stream)
{
    (void)in_sizes; (void)n_in; (void)out_size; (void)ws_size;

    const float* x0  = (const float*)d_in[0];
    const float* lat = (const float*)d_in[1];
    const float* dep = (const float*)d_in[2];
    const float* rg  = (const float*)d_in[3];
    const float* Wgi = (const float*)d_in[4];
    const float* bgi = (const float*)d_in[5];
    const float* Wgo = (const float*)d_in[6];
    const float* bgo = (const float*)d_in[7];
    const float* fiW = (const float*)d_in[8];
    const float* fib = (const float*)d_in[9];
    const float* foW = (const float*)d_in[10];
    const float* fob = (const float*)d_in[11];
    const float* lng = (const float*)d_in[12];
    const float* lnb = (const float*)d_in[13];

    char* ws = (char*)d_ws;
    size_t off = 0;
    auto alloc = [&](size_t bytes) {
        char* p = ws + off;
        off += (bytes + 255) & ~(size_t)255;
        return p;
    };
    u16* depb  = (u16*)alloc(2ull * B_ * N_ * N_);
    u16* latb  = (u16*)alloc(2ull * B_ * N_ * N_);
    u16* depTb = (u16*)alloc(2ull * B_ * N_ * N_);
    u16* latTb = (u16*)alloc(2ull * B_ * N_ * N_);
    u16* xT    = (u16*)alloc(2ull * B_ * D_ * N_);
    u16* axin  = (u16*)alloc(2ull * B_ * N_ * D_);
    u16* axout = (u16*)alloc(2ull * B_ * N_ * D_);
    float* gate = (float*)alloc(4ull * B_ * N_);
    float* xbuf = (float*)alloc(4ull * B_ * N_ * D_);
    u16* Wib = (u16*)alloc(2ull * 2 * H_ * D_);   // both layers
    u16* Wob = (u16*)alloc(2ull * 2 * H_ * D_);

    k_conv_adj<<<dim3(16, 16, 32), 256, 0, stream>>>(dep, lat, depb, latb, depTb, latTb);

    // layer 0 gate + x0 transpose; extra slices convert BOTH layers' weights
    k_gate_xt<<<dim3(32, B_ + 8), 256, 0, stream>>>(
        x0, rg, gate, xT, fiW, foW, Wib, Wob);

    // layer 0
    k_gemm_ax<<<dim3(256), 512, 0, stream>>>(
        depb, latb, depTb, latTb, xT, gate,
        Wgi, Wgo, bgi, bgo, x0, axin, axout);
    // fused: writes xbuf + layer-1 gate + layer-1 xT
    k_fc_ln<1><<<dim3(256), 512, 0, stream>>>(
        axin, axout, Wib, Wob, fib, fob, lng, lnb,
        xbuf, rg + D_, gate, xT);

    // layer 1
    k_gemm_ax<<<dim3(256), 512, 0, stream>>>(
        depb, latb, depTb, latTb, xT, gate,
        Wgi + D_, Wgo + D_, bgi + 1, bgo + 1, xbuf, axin, axout);
    k_fc_ln<0><<<dim3(256), 512, 0, stream>>>(
        axin, axout, Wib + (size_t)H_ * D_, Wob + (size_t)H_ * D_,
        fib + H_, fob + H_, lng + 2 * H_, lnb + 2 * H_,
        (float*)d_out, nullptr, nullptr, nullptr);
}